// Round 6
// baseline (5664.838 us; speedup 1.0000x reference)
//
#include <hip/hip_runtime.h>
#include <cstdint>
#include <cstddef>

#define DEVI __device__ __forceinline__

typedef __attribute__((ext_vector_type(8))) short bf16x8;
typedef __attribute__((ext_vector_type(4))) float f32x4;
typedef unsigned short ushort_t;
typedef unsigned int uint_t;

// problem dims (fixed)
constexpr int NB = 64;    // batch
constexpr int NTT = 512;  // seq len
constexpr int NI = 512;   // input feat
constexpr int NH = 1024;  // hidden
constexpr int NA = 512;   // out feat
constexpr int NG = 4096;  // 4*NH
constexpr int CHUNK = 64; // scan chunk (timesteps per launch)

DEVI float bf2f(ushort_t u) { union { uint_t i; float f; } v; v.i = ((uint_t)u) << 16; return v.f; }
DEVI ushort_t f2bf(float f) {
  union { float f; uint_t i; } v; v.f = f;
  uint_t x = v.i;
  return (ushort_t)((x + 0x7fffu + ((x >> 16) & 1u)) >> 16);
}

// clamped fast tanh: safe for |x| large (clamp before exp), bf16-accurate
DEVI float tanh_f(float x) {
  x = fminf(fmaxf(x, -15.f), 15.f);
  float e = __expf(2.f * x);
  return (e - 1.f) / (e + 1.f);
}

DEVI void gload_lds16(const void* g, void* l) {
  __builtin_amdgcn_global_load_lds((__attribute__((address_space(1))) void*)g,
                                   (__attribute__((address_space(3))) void*)l, 16, 0, 0);
}

// ---------------- cast fp32 -> bf16 ----------------
__global__ __launch_bounds__(256) void cast_f32_bf16(const float* __restrict__ in,
                                                     ushort_t* __restrict__ out, int n) {
  int i = (blockIdx.x * 256 + threadIdx.x) * 4;
  if (i >= n) return;
  float4 v = *(const float4*)(in + i);
  ushort4 o;
  o.x = f2bf(v.x); o.y = f2bf(v.y); o.z = f2bf(v.z); o.w = f2bf(v.w);
  *(ushort4*)(out + i) = o;
}

// ---------------- generic NT GEMM: C[M,N] = A[M,K] * B[N,K]^T ----------------
// MODE 0: fp32 out, +bias0                              (fc3 -> d_out)
// MODE 1: bf16 out, tanh(acc+bias0)                     (fc1 -> f)
// MODE 2: chunked gx: A rows are (b, t0+tl) of f [B,T,H]; bf16 out,
//         acc+bias0+bias1, scatter to gxc[tl][wg][b][g*16+u]
template <int MODE>
__global__ __launch_bounds__(256) void gemm_nt(const short* __restrict__ A,
                                               const short* __restrict__ Bm,
                                               const float* __restrict__ bias0,
                                               const float* __restrict__ bias1,
                                               void* __restrict__ Cout,
                                               int M, int N, int K, int t0) {
  __shared__ short As[128 * 32];
  __shared__ short Bs[128 * 32];
  const int tid = threadIdx.x;
  const int wave = tid >> 6, lane = tid & 63;
  const int m0 = blockIdx.y * 128, n0 = blockIdx.x * 128;
  const int wr = wave >> 1, wc = wave & 1;

  f32x4 zero = {0.f, 0.f, 0.f, 0.f};
  f32x4 acc[4][4];
#pragma unroll
  for (int i = 0; i < 4; ++i)
#pragma unroll
    for (int j = 0; j < 4; ++j) acc[i][j] = zero;

  const int lrow = lane >> 2;       // 0..15
  const int lk = (lane & 3) * 8;    // element offset within 32

  for (int kt = 0; kt < K; kt += 32) {
#pragma unroll
    for (int c = 0; c < 2; ++c) {
      int q = wave + 4 * c;              // chunk 0..7, uniform per wave
      int row = m0 + q * 16 + lrow;
      long arow = (MODE == 2) ? ((long)(row >> 6) * NTT + t0 + (row & 63)) : (long)row;
      gload_lds16(A + arow * K + kt + lk, As + q * 512);
      gload_lds16(Bm + (long)(n0 + q * 16 + lrow) * K + kt + lk, Bs + q * 512);
    }
    __syncthreads();  // drains vmcnt for global_load_lds

    bf16x8 av[4], bv[4];
#pragma unroll
    for (int i = 0; i < 4; ++i) {
      int row = wr * 64 + i * 16 + (lane & 15);
      av[i] = *(const bf16x8*)(As + row * 32 + (lane >> 4) * 8);
    }
#pragma unroll
    for (int j = 0; j < 4; ++j) {
      int col = wc * 64 + j * 16 + (lane & 15);
      bv[j] = *(const bf16x8*)(Bs + col * 32 + (lane >> 4) * 8);
    }
#pragma unroll
    for (int i = 0; i < 4; ++i)
#pragma unroll
      for (int j = 0; j < 4; ++j)
        acc[i][j] = __builtin_amdgcn_mfma_f32_16x16x32_bf16(av[i], bv[j], acc[i][j], 0, 0, 0);
    __syncthreads();
  }

  const int fq = lane >> 4, fr = lane & 15;
#pragma unroll
  for (int i = 0; i < 4; ++i) {
#pragma unroll
    for (int j = 0; j < 4; ++j) {
      int gcol = n0 + wc * 64 + j * 16 + fr;
      float bsum = bias0[gcol];
      if (MODE == 2) bsum += bias1[gcol];
#pragma unroll
      for (int r = 0; r < 4; ++r) {
        int gm = m0 + wr * 64 + i * 16 + fq * 4 + r;
        float v = acc[i][j][r] + bsum;
        if (MODE == 0) {
          ((float*)Cout)[(long)gm * N + gcol] = v;
        } else if (MODE == 1) {
          ((ushort_t*)Cout)[(long)gm * N + gcol] = f2bf(tanhf(v));
        } else {
          int b = gm >> 6, tl = gm & 63;  // chunk row = b*64 + tl
          int wgp = (gcol >> 4) & 63, g = gcol >> 10, u = gcol & 15;
          ((ushort_t*)Cout)[((((long)tl * 64 + wgp) * 64 + b) << 6) + g * 16 + u] = f2bf(v);
        }
      }
    }
  }
}

// ---------------- persistent LSTM scan (one chunk of CHUNK timesteps) ----------------
// 64 WGs x 512 threads. WG owns 64 gate rows = 16 hidden units (wg*16+u).
// LDS: wlds[64][1024] bf16 XOR-swizzled (byte ^= (n&7)<<4); pre[64][65] fp32.
// h passes through rotating hseq slots (relaxed agent stores -> LLC).
// Grid sync: per-WG flag cachelines; wave0 polls all 64; release = s_waitcnt
// vmcnt(0) (payload stores are agent-atomics); acquire = agent fence
// (buffer_inv) after poll so reader L2s drop any stale hseq/flag lines.
// KEY: areg[32] bulk-stage pinned by sched_barrier(0) -> all 32 h-loads in
// flight at once (one LLC/fabric latency instead of ~13 serialized trips).
__global__ __launch_bounds__(512, 2) void lstm_scan(const ushort_t* __restrict__ whh,
                                                    const ushort_t* __restrict__ gxc,  // [CHUNK][64][NB][64]
                                                    ushort_t* __restrict__ hseq,       // [CHUNK+1][NB][NH]
                                                    float* __restrict__ cbuf,          // [NB][NH]
                                                    ushort_t* __restrict__ hs,         // [NB][NTT][NH]
                                                    uint_t* __restrict__ flags,
                                                    int t0, uint_t tbase) {
  extern __shared__ char smem[];
  float* pre = (float*)(smem + 64 * NH * 2);  // [64][65] fp32
  const int wg = blockIdx.x, tid = threadIdx.x;
  const int wave = tid >> 6, lane = tid & 63;
  const int fq = lane >> 4, fr = lane & 15;

  // stage weights into swizzled LDS
  for (int idx = tid; idx < 64 * 128; idx += 512) {
    int n = idx >> 7, kc = idx & 127;  // kc: 16B chunk (8 bf16)
    int grow = (n >> 4) * NH + wg * 16 + (n & 15);
    bf16x8 w = *(const bf16x8*)(whh + (long)grow * NH + kc * 8);
    int byteoff = n * 2048 + ((kc * 16) ^ ((n & 7) << 4));
    *(bf16x8*)(smem + byteoff) = w;
  }
  const int cb = tid >> 3, cup = tid & 7;  // thread owns (b=cb, u=2*cup, 2*cup+1)
  float c0, c1;
  if (t0 == 0) {
    uint_t* p = (uint_t*)(hseq + cb * NH + wg * 16 + cup * 2);
    __hip_atomic_store(p, 0u, __ATOMIC_RELAXED, __HIP_MEMORY_SCOPE_AGENT);
    c0 = 0.f; c1 = 0.f;
  } else {
    c0 = cbuf[cb * NH + wg * 16 + cup * 2];
    c1 = cbuf[cb * NH + wg * 16 + cup * 2 + 1];
  }

  const int bb = (wave & 3) * 16;        // batch base for this wave
  const int nb0 = (wave >> 2) * 32;      // n base (two 16-tiles)
  const int abrow = bb + fr;             // A-frag row (batch)
  f32x4 zero = {0.f, 0.f, 0.f, 0.f};

  ushort_t gxr[8];
  auto prefetch = [&](int tl) {
#pragma unroll
    for (int jt = 0; jt < 2; ++jt) {
      int n = nb0 + jt * 16 + fr;
#pragma unroll
      for (int r = 0; r < 4; ++r) {
        int b = bb + fq * 4 + r;
        gxr[jt * 4 + r] = gxc[((((long)tl * 64 + wg) * 64 + b) << 6) + n];
      }
    }
  };
  auto poll = [&](uint_t t) {
    if (tid < 64) {
      uint_t* fp = flags + tid * 32;
      for (;;) {
        uint_t v = __hip_atomic_load(fp, __ATOMIC_RELAXED, __HIP_MEMORY_SCOPE_AGENT);
        if (__all(v >= t)) break;
        __builtin_amdgcn_s_sleep(1);
      }
      // agent acquire: drop stale L1/L2 lines before reading remote h
      __builtin_amdgcn_fence(__ATOMIC_ACQUIRE, "agent");
    }
  };

  // initial barrier: weights staged, h slot0 + c ready
  asm volatile("s_waitcnt vmcnt(0)" ::: "memory");
  __syncthreads();
  if (tid == 0)
    __hip_atomic_store(flags + wg * 32, tbase + 1, __ATOMIC_RELAXED, __HIP_MEMORY_SCOPE_AGENT);
  poll(tbase + 1);
  __syncthreads();
  prefetch(0);

  for (int tl = 0; tl < CHUNK; ++tl) {
    const ushort_t* hc = hseq + (size_t)tl * (NB * NH);
    // bulk-stage this step's A-fragments: 32 x 16B loads, ALL in flight.
    bf16x8 areg[32];
#pragma unroll
    for (int ks = 0; ks < 32; ++ks)
      areg[ks] = *(const bf16x8*)(hc + abrow * NH + ks * 32 + fq * 8);
    __builtin_amdgcn_sched_barrier(0);  // pin: no MFMA hoisted above, no load sunk below

    f32x4 acc0 = zero, acc1 = zero;
#pragma unroll
    for (int ks = 0; ks < 32; ++ks) {
      int n0 = nb0 + fr, n1 = nb0 + 16 + fr;
      int b0off = n0 * 2048 + ((ks * 64 + fq * 16) ^ ((n0 & 7) << 4));
      int b1off = n1 * 2048 + ((ks * 64 + fq * 16) ^ ((n1 & 7) << 4));
      bf16x8 w0 = *(const bf16x8*)(smem + b0off);
      bf16x8 w1 = *(const bf16x8*)(smem + b1off);
      acc0 = __builtin_amdgcn_mfma_f32_16x16x32_bf16(areg[ks], w0, acc0, 0, 0, 0);
      acc1 = __builtin_amdgcn_mfma_f32_16x16x32_bf16(areg[ks], w1, acc1, 0, 0, 0);
    }
    // preactivations (+gx) -> LDS
#pragma unroll
    for (int r = 0; r < 4; ++r) {
      int b = bb + fq * 4 + r;
      pre[b * 65 + nb0 + fr] = acc0[r] + bf2f(gxr[r]);
      pre[b * 65 + nb0 + 16 + fr] = acc1[r] + bf2f(gxr[4 + r]);
    }
    __syncthreads();
    // gates + state update for (cb, u0, u1)
    float h01[2];
#pragma unroll
    for (int k = 0; k < 2; ++k) {
      int u = cup * 2 + k;
      float xi = pre[cb * 65 + 0 * 16 + u];
      float xf = pre[cb * 65 + 1 * 16 + u];
      float xg = pre[cb * 65 + 2 * 16 + u];
      float xo = pre[cb * 65 + 3 * 16 + u];
      float ig = 1.f / (1.f + __expf(-xi));
      float fg = 1.f / (1.f + __expf(-xf));
      float gg = tanh_f(xg);
      float og = 1.f / (1.f + __expf(-xo));
      float& c = k ? c1 : c0;
      c = fg * c + ig * gg;
      h01[k] = og * tanh_f(c);
    }
    uint_t hpack = (uint_t)f2bf(h01[0]) | ((uint_t)f2bf(h01[1]) << 16);
    uint_t* hdst = (uint_t*)(hseq + (size_t)(tl + 1) * (NB * NH) + cb * NH + wg * 16 + cup * 2);
    __hip_atomic_store(hdst, hpack, __ATOMIC_RELAXED, __HIP_MEMORY_SCOPE_AGENT);
    if (tl == CHUNK - 1) {  // hand h(final) to next chunk's slot 0
      uint_t* h0 = (uint_t*)(hseq + cb * NH + wg * 16 + cup * 2);
      __hip_atomic_store(h0, hpack, __ATOMIC_RELAXED, __HIP_MEMORY_SCOPE_AGENT);
    }

    // ---- grid barrier: vmcnt-drain release, no wbl2 ----
    asm volatile("s_waitcnt vmcnt(0)" ::: "memory");  // h atomic stores acked at LLC
    __syncthreads();                                  // all threads of WG drained
    uint_t t = tbase + 2 + tl;
    if (tid == 0)
      __hip_atomic_store(flags + wg * 32, t, __ATOMIC_RELAXED, __HIP_MEMORY_SCOPE_AGENT);
    // off-critical-path work overlapped with the wait:
    *(uint_t*)(hs + ((size_t)cb * NTT + t0 + tl) * NH + wg * 16 + cup * 2) = hpack;
    if (tl + 1 < CHUNK) prefetch(tl + 1);
    poll(t);
    __syncthreads();
    asm volatile("" ::: "memory");
  }
  // persist c for next chunk
  cbuf[cb * NH + wg * 16 + cup * 2] = c0;
  cbuf[cb * NH + wg * 16 + cup * 2 + 1] = c1;
}

// ---------------- host ----------------
extern "C" void kernel_launch(void* const* d_in, const int* in_sizes, int n_in,
                              void* d_out, int out_size, void* d_ws, size_t ws_size,
                              hipStream_t stream) {
  const float* x = (const float*)d_in[0];
  const float* w1 = (const float*)d_in[1];
  const float* b1 = (const float*)d_in[2];
  const float* w_ih = (const float*)d_in[3];
  const float* w_hh = (const float*)d_in[4];
  const float* b_ih = (const float*)d_in[5];
  const float* b_hh = (const float*)d_in[6];
  const float* w3 = (const float*)d_in[7];
  const float* b3 = (const float*)d_in[8];

  char* ws = (char*)d_ws;
  size_t off = 0;
  auto alloc = [&](size_t bytes) {
    char* p = ws + off;
    off += (bytes + 255) & ~(size_t)255;
    return p;
  };
  ushort_t* w1b = (ushort_t*)alloc(sizeof(ushort_t) * NH * NI);
  ushort_t* wihb = (ushort_t*)alloc(sizeof(ushort_t) * NG * NH);
  ushort_t* whhb = (ushort_t*)alloc(sizeof(ushort_t) * NG * NH);
  ushort_t* w3b = (ushort_t*)alloc(sizeof(ushort_t) * NA * NH);
  ushort_t* fb = (ushort_t*)alloc(sizeof(ushort_t) * (size_t)NB * NTT * NH);  // f, then hs (in-place)
  float* cbuf = (float*)alloc(sizeof(float) * NB * NH);
  uint_t* flags = (uint_t*)alloc(sizeof(uint_t) * 64 * 32);
  if (off > ws_size) {
    hipMemsetAsync(d_out, 0xFF, 256, stream);  // NaN sentinel: ws too small
    return;
  }

  // scratch carved out of d_out (dead before fc3 writes d_out):
  ushort_t* xb = (ushort_t*)d_out;                           // bf16 x for fc1
  ushort_t* hseq = (ushort_t*)d_out;                         // [CHUNK+1][NB][NH] (reuses xb)
  ushort_t* gxc = (ushort_t*)d_out + (size_t)NB * NTT * NI;  // [CHUNK][64][NB][64]

  auto cast = [&](const float* src, ushort_t* dst, int n) {
    cast_f32_bf16<<<dim3((n / 4 + 255) / 256), dim3(256), 0, stream>>>(src, dst, n);
  };
  cast(x, xb, NB * NTT * NI);
  cast(w1, w1b, NH * NI);
  cast(w_ih, wihb, NG * NH);
  cast(w_hh, whhb, NG * NH);
  cast(w3, w3b, NA * NH);

  // fc1 + tanh -> f (bf16)
  gemm_nt<1><<<dim3(NH / 128, NB * NTT / 128), dim3(256), 0, stream>>>(
      (const short*)xb, (const short*)w1b, b1, nullptr, fb, NB * NTT, NH, NI, 0);

  hipMemsetAsync(flags, 0, sizeof(uint_t) * 64 * 32, stream);
  int ldsz = 64 * NH * 2 + 64 * 65 * 4;
  hipFuncSetAttribute(reinterpret_cast<const void*>(&lstm_scan),
                      hipFuncAttributeMaxDynamicSharedMemorySize, ldsz);

  for (int chunk = 0; chunk < NTT / CHUNK; ++chunk) {
    int t0 = chunk * CHUNK;
    gemm_nt<2><<<dim3(NG / 128, NB * CHUNK / 128), dim3(256), 0, stream>>>(
        (const short*)fb, (const short*)wihb, b_ih, b_hh, gxc, NB * CHUNK, NG, NH, t0);
    lstm_scan<<<dim3(64), dim3(512), ldsz, stream>>>(
        whhb, gxc, hseq, cbuf, fb, flags, t0, (uint_t)(chunk * (CHUNK + 1)));
  }

  // fc3 head -> d_out (fp32)
  gemm_nt<0><<<dim3(NA / 128, NB * NTT / 128), dim3(256), 0, stream>>>(
      (const short*)fb, (const short*)w3b, b3, nullptr, d_out, NB * NTT, NA, NH, 0);
}

// Round 7
// 3963.496 us; speedup vs baseline: 1.4293x; 1.4293x over previous
//
#include <hip/hip_runtime.h>
#include <cstdint>
#include <cstddef>

#define DEVI __device__ __forceinline__

typedef __attribute__((ext_vector_type(8))) short bf16x8;
typedef __attribute__((ext_vector_type(4))) float f32x4;
typedef unsigned short ushort_t;
typedef unsigned int uint_t;

// problem dims (fixed)
constexpr int NB = 64;    // batch
constexpr int NTT = 512;  // seq len
constexpr int NI = 512;   // input feat
constexpr int NH = 1024;  // hidden
constexpr int NA = 512;   // out feat
constexpr int NG = 4096;  // 4*NH
constexpr int CHUNK = 64; // scan chunk (timesteps per launch)

DEVI float bf2f(ushort_t u) { union { uint_t i; float f; } v; v.i = ((uint_t)u) << 16; return v.f; }
DEVI ushort_t f2bf(float f) {
  union { float f; uint_t i; } v; v.f = f;
  uint_t x = v.i;
  return (ushort_t)((x + 0x7fffu + ((x >> 16) & 1u)) >> 16);
}

// clamped fast tanh: safe for |x| large (clamp before exp), bf16-accurate
DEVI float tanh_f(float x) {
  x = fminf(fmaxf(x, -15.f), 15.f);
  float e = __expf(2.f * x);
  return (e - 1.f) / (e + 1.f);
}

DEVI void gload_lds16(const void* g, void* l) {
  __builtin_amdgcn_global_load_lds((__attribute__((address_space(1))) void*)g,
                                   (__attribute__((address_space(3))) void*)l, 16, 0, 0);
}

// ---------------- cast fp32 -> bf16 ----------------
__global__ __launch_bounds__(256) void cast_f32_bf16(const float* __restrict__ in,
                                                     ushort_t* __restrict__ out, int n) {
  int i = (blockIdx.x * 256 + threadIdx.x) * 4;
  if (i >= n) return;
  float4 v = *(const float4*)(in + i);
  ushort4 o;
  o.x = f2bf(v.x); o.y = f2bf(v.y); o.z = f2bf(v.z); o.w = f2bf(v.w);
  *(ushort4*)(out + i) = o;
}

// ---------------- generic NT GEMM: C[M,N] = A[M,K] * B[N,K]^T ----------------
// MODE 0: fp32 out, +bias0                              (fc3 -> d_out)
// MODE 1: bf16 out, tanh(acc+bias0)                     (fc1 -> f)
// MODE 2: chunked gx: A rows are (b, t0+tl) of f [B,T,H]; bf16 out,
//         acc+bias0+bias1, scatter to gxc[tl][wg][b][g*16+u]
template <int MODE>
__global__ __launch_bounds__(256) void gemm_nt(const short* __restrict__ A,
                                               const short* __restrict__ Bm,
                                               const float* __restrict__ bias0,
                                               const float* __restrict__ bias1,
                                               void* __restrict__ Cout,
                                               int M, int N, int K, int t0) {
  __shared__ short As[128 * 32];
  __shared__ short Bs[128 * 32];
  const int tid = threadIdx.x;
  const int wave = tid >> 6, lane = tid & 63;
  const int m0 = blockIdx.y * 128, n0 = blockIdx.x * 128;
  const int wr = wave >> 1, wc = wave & 1;

  f32x4 zero = {0.f, 0.f, 0.f, 0.f};
  f32x4 acc[4][4];
#pragma unroll
  for (int i = 0; i < 4; ++i)
#pragma unroll
    for (int j = 0; j < 4; ++j) acc[i][j] = zero;

  const int lrow = lane >> 2;       // 0..15
  const int lk = (lane & 3) * 8;    // element offset within 32

  for (int kt = 0; kt < K; kt += 32) {
#pragma unroll
    for (int c = 0; c < 2; ++c) {
      int q = wave + 4 * c;              // chunk 0..7, uniform per wave
      int row = m0 + q * 16 + lrow;
      long arow = (MODE == 2) ? ((long)(row >> 6) * NTT + t0 + (row & 63)) : (long)row;
      gload_lds16(A + arow * K + kt + lk, As + q * 512);
      gload_lds16(Bm + (long)(n0 + q * 16 + lrow) * K + kt + lk, Bs + q * 512);
    }
    __syncthreads();  // drains vmcnt for global_load_lds

    bf16x8 av[4], bv[4];
#pragma unroll
    for (int i = 0; i < 4; ++i) {
      int row = wr * 64 + i * 16 + (lane & 15);
      av[i] = *(const bf16x8*)(As + row * 32 + (lane >> 4) * 8);
    }
#pragma unroll
    for (int j = 0; j < 4; ++j) {
      int col = wc * 64 + j * 16 + (lane & 15);
      bv[j] = *(const bf16x8*)(Bs + col * 32 + (lane >> 4) * 8);
    }
#pragma unroll
    for (int i = 0; i < 4; ++i)
#pragma unroll
      for (int j = 0; j < 4; ++j)
        acc[i][j] = __builtin_amdgcn_mfma_f32_16x16x32_bf16(av[i], bv[j], acc[i][j], 0, 0, 0);
    __syncthreads();
  }

  const int fq = lane >> 4, fr = lane & 15;
#pragma unroll
  for (int i = 0; i < 4; ++i) {
#pragma unroll
    for (int j = 0; j < 4; ++j) {
      int gcol = n0 + wc * 64 + j * 16 + fr;
      float bsum = bias0[gcol];
      if (MODE == 2) bsum += bias1[gcol];
#pragma unroll
      for (int r = 0; r < 4; ++r) {
        int gm = m0 + wr * 64 + i * 16 + fq * 4 + r;
        float v = acc[i][j][r] + bsum;
        if (MODE == 0) {
          ((float*)Cout)[(long)gm * N + gcol] = v;
        } else if (MODE == 1) {
          ((ushort_t*)Cout)[(long)gm * N + gcol] = f2bf(tanhf(v));
        } else {
          int b = gm >> 6, tl = gm & 63;  // chunk row = b*64 + tl
          int wgp = (gcol >> 4) & 63, g = gcol >> 10, u = gcol & 15;
          ((ushort_t*)Cout)[((((long)tl * 64 + wgp) * 64 + b) << 6) + g * 16 + u] = f2bf(v);
        }
      }
    }
  }
}

// ---------------- persistent LSTM scan (one chunk of CHUNK timesteps) ----------------
// 64 WGs x 512 threads. WG owns 64 gate rows = 16 hidden units (wg*16+u).
// Wave mapping (R7): wave = g*4 + w2; g = K-half (512 cols), w2 = batch group
// (16 batches). Each wave reads a DISJOINT 16KB slice of h (128KB/WG total,
// was 256KB). K-half partials are combined through pre[] in LDS.
// Weight LDS is FRAGMENT-ORDERED: the B-fragment of (ksg,nt) is a contiguous
// 1KB block read at base+lane*16 -> zero bank conflicts (was 8-way).
// Grid sync: per-WG flag lines, wave0 polls; release = s_waitcnt vmcnt(0)
// (payload stores are agent-atomics); one agent-acquire fence per chunk.
__global__ __launch_bounds__(512, 2) void lstm_scan(const ushort_t* __restrict__ whh,
                                                    const ushort_t* __restrict__ gxc,  // [CHUNK][64][NB][64]
                                                    ushort_t* __restrict__ hseq,       // [CHUNK+1][NB][NH]
                                                    float* __restrict__ cbuf,          // [NB][NH]
                                                    ushort_t* __restrict__ hs,         // [NB][NTT][NH]
                                                    uint_t* __restrict__ flags,
                                                    int t0, uint_t tbase) {
  extern __shared__ char smem[];
  float* pre = (float*)(smem + 64 * NH * 2);  // [64][64] fp32 (16KB)
  const int wg = blockIdx.x, tid = threadIdx.x;
  const int wave = tid >> 6, lane = tid & 63;
  const int fq = lane >> 4, fr = lane & 15;
  const int g = wave >> 2, w2 = wave & 3;

  // stage weights into fragment-ordered LDS:
  // frag[(ksg*4+nt)*64 + fq*16 + fr] <- W[n=nt*16+fr][k=ksg*32+fq*8 ..+8]
  for (int idx = tid; idx < 64 * 128; idx += 512) {
    int n = idx >> 7, kc = idx & 127;  // kc: 16B chunk (8 bf16) along K
    int grow = (n >> 4) * NH + wg * 16 + (n & 15);
    bf16x8 w = *(const bf16x8*)(whh + (long)grow * NH + kc * 8);
    int frag = ((kc >> 2) * 4 + (n >> 4)) * 64 + (kc & 3) * 16 + (n & 15);
    *(bf16x8*)(smem + frag * 16) = w;
  }
  const int cb = tid >> 3, cup = tid & 7;  // thread owns (b=cb, u=2*cup, 2*cup+1)
  float c0, c1;
  if (t0 == 0) {
    uint_t* p = (uint_t*)(hseq + cb * NH + wg * 16 + cup * 2);
    __hip_atomic_store(p, 0u, __ATOMIC_RELAXED, __HIP_MEMORY_SCOPE_AGENT);
    c0 = 0.f; c1 = 0.f;
  } else {
    c0 = cbuf[cb * NH + wg * 16 + cup * 2];
    c1 = cbuf[cb * NH + wg * 16 + cup * 2 + 1];
  }

  const int bb = w2 * 16;          // batch base for this wave
  const int abrow = bb + fr;       // A-frag row (batch)
  const int lane16 = lane * 16;
  f32x4 zero = {0.f, 0.f, 0.f, 0.f};

  ushort_t gxr[16];
  auto prefetch = [&](int tl) {  // g==0 waves only: all 64 n for own batches
#pragma unroll
    for (int nt = 0; nt < 4; ++nt)
#pragma unroll
      for (int r = 0; r < 4; ++r)
        gxr[nt * 4 + r] =
            gxc[((((long)tl * 64 + wg) * 64 + (bb + fq * 4 + r)) << 6) + nt * 16 + fr];
  };
  auto poll = [&](uint_t t) {
    if (tid < 64) {
      uint_t* fp = flags + tid * 32;
      for (;;) {
        uint_t v = __hip_atomic_load(fp, __ATOMIC_RELAXED, __HIP_MEMORY_SCOPE_AGENT);
        if (__all(v >= t)) break;
        __builtin_amdgcn_s_sleep(1);
      }
    }
  };

  // initial barrier: weights staged, h slot0 + c ready
  asm volatile("s_waitcnt vmcnt(0)" ::: "memory");
  __syncthreads();
  if (tid == 0)
    __hip_atomic_store(flags + wg * 32, tbase + 1, __ATOMIC_RELAXED, __HIP_MEMORY_SCOPE_AGENT);
  poll(tbase + 1);
  // one agent acquire per chunk: drop any stale L1/L2 lines of hseq/gxc
  __builtin_amdgcn_fence(__ATOMIC_ACQUIRE, "agent");
  __syncthreads();
  if (g == 0) prefetch(0);

  for (int tl = 0; tl < CHUNK; ++tl) {
    const ushort_t* hc = hseq + (size_t)tl * (NB * NH);
    // bulk-stage this wave's disjoint K-half slice: 16 x 16B loads in flight
    bf16x8 areg[16];
#pragma unroll
    for (int ks = 0; ks < 16; ++ks) {
      int ksg = g * 16 + ((ks + wg) & 15);  // per-WG rotation de-bursts LLC lines
      areg[ks] = *(const bf16x8*)(hc + abrow * NH + ksg * 32 + fq * 8);
    }
    __builtin_amdgcn_sched_barrier(0);

    f32x4 acc[4] = {zero, zero, zero, zero};
#pragma unroll
    for (int ks = 0; ks < 16; ++ks) {
      int ksg = g * 16 + ((ks + wg) & 15);
#pragma unroll
      for (int nt = 0; nt < 4; ++nt) {
        bf16x8 w = *(const bf16x8*)(smem + ((ksg * 4 + nt) << 10) + lane16);
        acc[nt] = __builtin_amdgcn_mfma_f32_16x16x32_bf16(areg[ks], w, acc[nt], 0, 0, 0);
      }
    }
    // combine K-half partials via pre[]
    if (g == 1) {
#pragma unroll
      for (int nt = 0; nt < 4; ++nt)
#pragma unroll
        for (int r = 0; r < 4; ++r)
          pre[(bb + fq * 4 + r) * 64 + nt * 16 + fr] = acc[nt][r];
    }
    __syncthreads();
    if (g == 0) {
#pragma unroll
      for (int nt = 0; nt < 4; ++nt)
#pragma unroll
        for (int r = 0; r < 4; ++r) {
          int ii = (bb + fq * 4 + r) * 64 + nt * 16 + fr;
          pre[ii] = pre[ii] + acc[nt][r] + bf2f(gxr[nt * 4 + r]);
        }
    }
    __syncthreads();
    // gates + state update for (cb, u0, u1)
    float h01[2];
#pragma unroll
    for (int k = 0; k < 2; ++k) {
      int u = cup * 2 + k;
      float xi = pre[cb * 64 + 0 * 16 + u];
      float xf = pre[cb * 64 + 1 * 16 + u];
      float xg = pre[cb * 64 + 2 * 16 + u];
      float xo = pre[cb * 64 + 3 * 16 + u];
      float ig = 1.f / (1.f + __expf(-xi));
      float fg = 1.f / (1.f + __expf(-xf));
      float gg = tanh_f(xg);
      float og = 1.f / (1.f + __expf(-xo));
      float& c = k ? c1 : c0;
      c = fg * c + ig * gg;
      h01[k] = og * tanh_f(c);
    }
    uint_t hpack = (uint_t)f2bf(h01[0]) | ((uint_t)f2bf(h01[1]) << 16);
    uint_t* hdst = (uint_t*)(hseq + (size_t)(tl + 1) * (NB * NH) + cb * NH + wg * 16 + cup * 2);
    __hip_atomic_store(hdst, hpack, __ATOMIC_RELAXED, __HIP_MEMORY_SCOPE_AGENT);
    if (tl == CHUNK - 1) {  // hand h(final) to next chunk's slot 0
      uint_t* h0 = (uint_t*)(hseq + cb * NH + wg * 16 + cup * 2);
      __hip_atomic_store(h0, hpack, __ATOMIC_RELAXED, __HIP_MEMORY_SCOPE_AGENT);
    }

    // ---- grid barrier: vmcnt-drain release, no wbl2 ----
    asm volatile("s_waitcnt vmcnt(0)" ::: "memory");  // h atomic stores acked at LLC
    __syncthreads();                                  // all threads of WG drained
    uint_t t = tbase + 2 + tl;
    if (tid == 0)
      __hip_atomic_store(flags + wg * 32, t, __ATOMIC_RELAXED, __HIP_MEMORY_SCOPE_AGENT);
    // off-critical-path work overlapped with the wait:
    *(uint_t*)(hs + ((size_t)cb * NTT + t0 + tl) * NH + wg * 16 + cup * 2) = hpack;
    if (g == 0 && tl + 1 < CHUNK) prefetch(tl + 1);
    poll(t);
    __syncthreads();
    asm volatile("" ::: "memory");
  }
  // persist c for next chunk
  cbuf[cb * NH + wg * 16 + cup * 2] = c0;
  cbuf[cb * NH + wg * 16 + cup * 2 + 1] = c1;
}

// ---------------- host ----------------
extern "C" void kernel_launch(void* const* d_in, const int* in_sizes, int n_in,
                              void* d_out, int out_size, void* d_ws, size_t ws_size,
                              hipStream_t stream) {
  const float* x = (const float*)d_in[0];
  const float* w1 = (const float*)d_in[1];
  const float* b1 = (const float*)d_in[2];
  const float* w_ih = (const float*)d_in[3];
  const float* w_hh = (const float*)d_in[4];
  const float* b_ih = (const float*)d_in[5];
  const float* b_hh = (const float*)d_in[6];
  const float* w3 = (const float*)d_in[7];
  const float* b3 = (const float*)d_in[8];

  char* ws = (char*)d_ws;
  size_t off = 0;
  auto alloc = [&](size_t bytes) {
    char* p = ws + off;
    off += (bytes + 255) & ~(size_t)255;
    return p;
  };
  ushort_t* w1b = (ushort_t*)alloc(sizeof(ushort_t) * NH * NI);
  ushort_t* wihb = (ushort_t*)alloc(sizeof(ushort_t) * NG * NH);
  ushort_t* whhb = (ushort_t*)alloc(sizeof(ushort_t) * NG * NH);
  ushort_t* w3b = (ushort_t*)alloc(sizeof(ushort_t) * NA * NH);
  ushort_t* fb = (ushort_t*)alloc(sizeof(ushort_t) * (size_t)NB * NTT * NH);  // f, then hs (in-place)
  float* cbuf = (float*)alloc(sizeof(float) * NB * NH);
  uint_t* flags = (uint_t*)alloc(sizeof(uint_t) * 64 * 32);
  if (off > ws_size) {
    hipMemsetAsync(d_out, 0xFF, 256, stream);  // NaN sentinel: ws too small
    return;
  }

  // scratch carved out of d_out (dead before fc3 writes d_out):
  ushort_t* xb = (ushort_t*)d_out;                           // bf16 x for fc1
  ushort_t* hseq = (ushort_t*)d_out;                         // [CHUNK+1][NB][NH] (reuses xb)
  ushort_t* gxc = (ushort_t*)d_out + (size_t)NB * NTT * NI;  // [CHUNK][64][NB][64]

  auto cast = [&](const float* src, ushort_t* dst, int n) {
    cast_f32_bf16<<<dim3((n / 4 + 255) / 256), dim3(256), 0, stream>>>(src, dst, n);
  };
  cast(x, xb, NB * NTT * NI);
  cast(w1, w1b, NH * NI);
  cast(w_ih, wihb, NG * NH);
  cast(w_hh, whhb, NG * NH);
  cast(w3, w3b, NA * NH);

  // fc1 + tanh -> f (bf16)
  gemm_nt<1><<<dim3(NH / 128, NB * NTT / 128), dim3(256), 0, stream>>>(
      (const short*)xb, (const short*)w1b, b1, nullptr, fb, NB * NTT, NH, NI, 0);

  hipMemsetAsync(flags, 0, sizeof(uint_t) * 64 * 32, stream);
  int ldsz = 64 * NH * 2 + 64 * 64 * 4;
  hipFuncSetAttribute(reinterpret_cast<const void*>(&lstm_scan),
                      hipFuncAttributeMaxDynamicSharedMemorySize, ldsz);

  for (int chunk = 0; chunk < NTT / CHUNK; ++chunk) {
    int t0 = chunk * CHUNK;
    gemm_nt<2><<<dim3(NG / 128, NB * CHUNK / 128), dim3(256), 0, stream>>>(
        (const short*)fb, (const short*)wihb, b_ih, b_hh, gxc, NB * CHUNK, NG, NH, t0);
    lstm_scan<<<dim3(64), dim3(512), ldsz, stream>>>(
        whhb, gxc, hseq, cbuf, fb, flags, t0, (uint_t)(chunk * (CHUNK + 1)));
  }

  // fc3 head -> d_out (fp32)
  gemm_nt<0><<<dim3(NA / 128, NB * NTT / 128), dim3(256), 0, stream>>>(
      (const short*)fb, (const short*)w3b, b3, nullptr, d_out, NB * NTT, NA, NH, 0);
}